// Round 4
// baseline (434.654 us; speedup 1.0000x reference)
//
#include <hip/hip_runtime.h>
#include <hip/hip_bf16.h>
#include <stdint.h>

// Round-7: structural change. Model (validated over rounds 0-3): wall is
// latency-critical random line requests per edge (2: W line + x line) against
// a ~32-outstanding per-CU fill cap at ~300cy avg latency. Bytes/BW are not
// the wall (nt-load, slicing, nt-store experiments). So: counting-sort edges
// by input_idx>>10 into 1024 buckets; main kernel stages each bucket's value
// slice (1024 rows x 16B bf16 = 16KB) in LDS and serves x from LDS broadcast.
// Requests/edge: 2 -> ~1 (W only). Out written nt (scattered now; protect L2
// for the 8.4MB W table). V is converted f32->bf16 on the fly during slice
// staging (identical RNE numerics to the old vbf table; absmax stays 0.125).

typedef float          f32x4 __attribute__((ext_vector_type(4)));
typedef unsigned int   u32x4 __attribute__((ext_vector_type(4)));
typedef unsigned short u16x4 __attribute__((ext_vector_type(4)));

#define NB  1024   // buckets (fixed; scan kernel uses NB threads)
#define RPB 1024   // max value-rows per bucket -> 16KB LDS slice

static __device__ __forceinline__ float bflo(uint32_t u) {
    union { uint32_t u; float f; } c; c.u = u << 16; return c.f;
}
static __device__ __forceinline__ float bfhi(uint32_t u) {
    union { uint32_t u; float f; } c; c.u = u & 0xffff0000u; return c.f;
}
static __device__ __forceinline__ uint32_t pack_bf16x2(float lo, float hi) {
    uint32_t l = __bfloat16_as_ushort(__float2bfloat16(lo));
    uint32_t h = __bfloat16_as_ushort(__float2bfloat16(hi));
    return l | (h << 16);
}

// ---- W table fp32 -> bf16 (RNE) ----
__global__ __launch_bounds__(256) void convert_w_kernel(
    const f32x4* __restrict__ src, u16x4* __restrict__ dst, int n4)
{
    int i = blockIdx.x * blockDim.x + threadIdx.x;
    if (i >= n4) return;
    f32x4 v = src[i];
    u16x4 r;
    r.x = __bfloat16_as_ushort(__float2bfloat16(v.x));
    r.y = __bfloat16_as_ushort(__float2bfloat16(v.y));
    r.z = __bfloat16_as_ushort(__float2bfloat16(v.z));
    r.w = __bfloat16_as_ushort(__float2bfloat16(v.w));
    dst[i] = r;
}

// ---- sort pass 0: zero global histogram ----
__global__ __launch_bounds__(NB) void zero_hist_kernel(uint32_t* __restrict__ g)
{
    g[threadIdx.x] = 0u;
}

// ---- sort pass 1: global histogram of iidx buckets ----
__global__ __launch_bounds__(256) void hist_kernel(
    const int* __restrict__ input_idx, uint32_t* __restrict__ ghist,
    int E, int bshift)
{
    __shared__ uint32_t h[NB];
    for (int i = threadIdx.x; i < NB; i += 256) h[i] = 0u;
    __syncthreads();
    int base = blockIdx.x * 8192;
    #pragma unroll
    for (int k = 0; k < 32; ++k) {
        int ei = base + k * 256 + threadIdx.x;
        if (ei < E) {
            uint32_t b = ((uint32_t)input_idx[ei]) >> bshift;
            atomicAdd(&h[b], 1u);
        }
    }
    __syncthreads();
    for (int i = threadIdx.x; i < NB; i += 256) {
        uint32_t v = h[i];
        if (v) atomicAdd(&ghist[i], v);
    }
}

// ---- sort pass 2: exclusive scan (single block of NB threads) ----
__global__ __launch_bounds__(NB) void scan_kernel(
    const uint32_t* __restrict__ ghist,
    uint32_t* __restrict__ bucket_base,   // [NB+1]
    uint32_t* __restrict__ cursor)        // [NB]
{
    __shared__ uint32_t s[NB];
    int t = threadIdx.x;
    uint32_t orig = ghist[t];
    s[t] = orig;
    __syncthreads();
    for (int off = 1; off < NB; off <<= 1) {
        uint32_t v = (t >= off) ? s[t - off] : 0u;
        __syncthreads();
        s[t] += v;
        __syncthreads();
    }
    uint32_t excl = s[t] - orig;
    bucket_base[t] = excl;
    cursor[t] = excl;
    if (t == NB - 1) bucket_base[NB] = s[t];
}

// ---- sort pass 3: scatter {key, e} records into bucket regions ----
__global__ __launch_bounds__(1024) void scatter_kernel(
    const int* __restrict__ input_idx,
    const int* __restrict__ weight_idx,
    uint32_t*  __restrict__ cursor,
    uint2*     __restrict__ sorted,
    int E, int bshift)
{
    __shared__ uint32_t h[NB];
    int t = threadIdx.x;
    h[t] = 0u;
    __syncthreads();
    int base = blockIdx.x * 8192;
    uint32_t ii[8], wi[8];
    #pragma unroll
    for (int k = 0; k < 8; ++k) {
        int ei = base + k * 1024 + t;
        if (ei < E) {
            ii[k] = (uint32_t)input_idx[ei];
            wi[k] = (uint32_t)weight_idx[ei];
            atomicAdd(&h[ii[k] >> bshift], 1u);
        }
    }
    __syncthreads();
    uint32_t cnt = h[t];
    uint32_t gb = 0u;
    if (cnt) gb = atomicAdd(&cursor[t], cnt);   // claim contiguous range
    h[t] = gb;                                  // own slot only: no race
    __syncthreads();
    uint32_t mask = (1u << bshift) - 1u;
    #pragma unroll
    for (int k = 0; k < 8; ++k) {
        int ei = base + k * 1024 + t;
        if (ei < E) {
            uint32_t b = ii[k] >> bshift;
            uint32_t pos = atomicAdd(&h[b], 1u);
            uint2 rec;
            rec.x = ((ii[k] & mask) << 16) | wi[k];
            rec.y = (uint32_t)ei;
            sorted[pos] = rec;
        }
    }
}

// ---- main: 2 blocks per bucket; x from LDS slice; W gathered (1 line/edge) ----
__global__ __launch_bounds__(256) void edge_linear_sorted_kernel(
    const float*    __restrict__ values,      // fp32[rows][8]
    const uint32_t* __restrict__ wbf,         // bf16[numW][8][8] as u32[.][32]
    const uint2*    __restrict__ sorted,      // [E] {key, e}
    const uint32_t* __restrict__ bucket_base, // [NB+1]
    float*          __restrict__ out,         // fp32[E][8]
    int rows, int bshift)
{
    __shared__ u32x4 vlds[RPB];               // 16KB bf16 slice
    int b = blockIdx.x >> 1;
    int c = blockIdx.x & 1;
    int s    = (int)bucket_base[b];
    int tend = (int)bucket_base[b + 1];
    int half = (tend - s + 1) >> 1;
    int lo = s + c * half;
    int hi = min(tend, lo + half);

    int spb   = 1 << bshift;                  // rows in this slice (<= RPB)
    int rbase = b << bshift;
    for (int r = threadIdx.x; r < spb; r += 256) {
        int row = rbase + r;
        u32x4 v = {0u, 0u, 0u, 0u};
        if (row < rows) {
            const f32x4* vp = (const f32x4*)(values + (size_t)row * 8u);
            f32x4 a0 = vp[0];
            f32x4 a1 = vp[1];
            v.x = pack_bf16x2(a0.x, a0.y);
            v.y = pack_bf16x2(a0.z, a0.w);
            v.z = pack_bf16x2(a1.x, a1.y);
            v.w = pack_bf16x2(a1.z, a1.w);
        }
        vlds[r] = v;
    }
    __syncthreads();

    int g = threadIdx.x >> 3;                 // 32 edge-groups per block
    int o = threadIdx.x & 7;

    for (int p = lo + g; p < hi; p += 32) {
        uint2 rec = sorted[p];                // 8 lanes same addr: broadcast
        uint32_t local = rec.x >> 16;
        uint32_t widx  = rec.x & 0xffffu;
        uint32_t e     = rec.y;
        u32x4 xv = vlds[local];               // LDS broadcast within group
        u32x4 wv = *(const u32x4*)(wbf + (size_t)widx * 32u + (uint32_t)o * 4u);
        float acc = 0.0f;
        acc = fmaf(bflo(wv.x), bflo(xv.x), acc);
        acc = fmaf(bfhi(wv.x), bfhi(xv.x), acc);
        acc = fmaf(bflo(wv.y), bflo(xv.y), acc);
        acc = fmaf(bfhi(wv.y), bfhi(xv.y), acc);
        acc = fmaf(bflo(wv.z), bflo(xv.z), acc);
        acc = fmaf(bfhi(wv.z), bfhi(xv.z), acc);
        acc = fmaf(bflo(wv.w), bflo(xv.w), acc);
        acc = fmaf(bfhi(wv.w), bfhi(xv.w), acc);
        __builtin_nontemporal_store(acc, &out[(size_t)e * 8u + (uint32_t)o]);
    }
}

// ---- fallback: round-2 kernel (bf16 W+V tables), plain stores ----
__global__ __launch_bounds__(256) void edge_linear_bf16wv_kernel(
    const uint32_t* __restrict__ vbf,
    const uint32_t* __restrict__ wbf,
    const int*      __restrict__ input_idx,
    const int*      __restrict__ weight_idx,
    float*          __restrict__ out,
    int E)
{
    int gid = blockIdx.x * blockDim.x + threadIdx.x;
    int e = gid >> 3;
    if (e >= E) return;
    int o = gid & 7;
    int iidx = input_idx[e];
    int widx = weight_idx[e];
    const u32x4* xp = (const u32x4*)(vbf + (size_t)iidx * 4u);
    const u32x4* wp = (const u32x4*)(wbf + (size_t)widx * 32u + (uint32_t)o * 4u);
    u32x4 wv = *wp;
    u32x4 xv = *xp;
    float acc = 0.0f;
    acc = fmaf(bflo(wv.x), bflo(xv.x), acc);
    acc = fmaf(bfhi(wv.x), bfhi(xv.x), acc);
    acc = fmaf(bflo(wv.y), bflo(xv.y), acc);
    acc = fmaf(bfhi(wv.y), bfhi(xv.y), acc);
    acc = fmaf(bflo(wv.z), bflo(xv.z), acc);
    acc = fmaf(bfhi(wv.z), bfhi(xv.z), acc);
    acc = fmaf(bflo(wv.w), bflo(xv.w), acc);
    acc = fmaf(bfhi(wv.w), bfhi(xv.w), acc);
    out[gid] = acc;
}

__global__ __launch_bounds__(256) void convert_v_kernel(
    const f32x4* __restrict__ src, u16x4* __restrict__ dst, int n4)
{
    int i = blockIdx.x * blockDim.x + threadIdx.x;
    if (i >= n4) return;
    f32x4 v = src[i];
    u16x4 r;
    r.x = __bfloat16_as_ushort(__float2bfloat16(v.x));
    r.y = __bfloat16_as_ushort(__float2bfloat16(v.y));
    r.z = __bfloat16_as_ushort(__float2bfloat16(v.z));
    r.w = __bfloat16_as_ushort(__float2bfloat16(v.w));
    dst[i] = r;
}

// ---- f32 fallback ----
__global__ __launch_bounds__(256) void edge_linear_f32_kernel(
    const float* __restrict__ values,
    const float* __restrict__ weights,
    const int*   __restrict__ input_idx,
    const int*   __restrict__ weight_idx,
    float*       __restrict__ out,
    int E)
{
    int gid = blockIdx.x * blockDim.x + threadIdx.x;
    int e = gid >> 3;
    if (e >= E) return;
    int o = gid & 7;
    int iidx = input_idx[e];
    int widx = weight_idx[e];
    const float4* xp = (const float4*)(values  + (size_t)iidx * 8u);
    const float4* wp = (const float4*)(weights + (size_t)widx * 64u + (uint32_t)o * 8u);
    float4 x0 = xp[0], x1 = xp[1], w0 = wp[0], w1 = wp[1];
    float acc = 0.0f;
    acc = fmaf(w0.x, x0.x, acc); acc = fmaf(w0.y, x0.y, acc);
    acc = fmaf(w0.z, x0.z, acc); acc = fmaf(w0.w, x0.w, acc);
    acc = fmaf(w1.x, x1.x, acc); acc = fmaf(w1.y, x1.y, acc);
    acc = fmaf(w1.z, x1.z, acc); acc = fmaf(w1.w, x1.w, acc);
    out[gid] = acc;
}

extern "C" void kernel_launch(void* const* d_in, const int* in_sizes, int n_in,
                              void* d_out, int out_size, void* d_ws, size_t ws_size,
                              hipStream_t stream) {
    const float* values     = (const float*)d_in[0];
    const float* weights    = (const float*)d_in[1];
    const int*   input_idx  = (const int*)d_in[2];
    const int*   weight_idx = (const int*)d_in[3];
    float*       out        = (float*)d_out;

    int NV = in_sizes[0];               // floats in value table
    int NW = in_sizes[1];               // floats in weight table
    int E  = in_sizes[2];               // edges

    int rows = NV / 8;
    int numW = NW / 64;

    auto aln = [](size_t x) { return (x + 255u) & ~(size_t)255u; };

    // sorted-path workspace layout
    size_t off_w    = 0;
    size_t off_sort = aln((size_t)NW * 2u);
    size_t off_hist = off_sort + aln((size_t)E * 8u);
    size_t off_base = off_hist + aln((size_t)NB * 4u);
    size_t off_cur  = off_base + aln((size_t)(NB + 1) * 4u);
    size_t need_sort = off_cur + aln((size_t)NB * 4u);   // ~42 MB

    // bucket shift: smallest s with (rows-1)>>s < NB
    int bshift = 0;
    while (bshift < 20 && (((uint32_t)(rows - 1)) >> bshift) >= NB) bshift++;
    bool sortable = (numW <= 65536) && (rows >= 1) && ((1 << bshift) <= RPB);

    // fallback (round-2) layout
    size_t need_w  = (size_t)NW * sizeof(uint16_t);
    size_t v_off   = aln(need_w);
    size_t need_wv = v_off + (size_t)NV * sizeof(uint16_t);

    long long threads = (long long)E * 8;
    int block = 256;
    int grid = (int)((threads + block - 1) / block);

    if (sortable && ws_size >= need_sort) {
        uint16_t* wbf    = (uint16_t*)((char*)d_ws + off_w);
        uint2*    sorted = (uint2*)   ((char*)d_ws + off_sort);
        uint32_t* ghist  = (uint32_t*)((char*)d_ws + off_hist);
        uint32_t* bbase  = (uint32_t*)((char*)d_ws + off_base);
        uint32_t* cursor = (uint32_t*)((char*)d_ws + off_cur);

        int wn4 = NW / 4;
        convert_w_kernel<<<(wn4 + 255) / 256, 256, 0, stream>>>(
            (const f32x4*)weights, (u16x4*)wbf, wn4);

        int sblocks = (E + 8191) / 8192;
        zero_hist_kernel<<<1, NB, 0, stream>>>(ghist);
        hist_kernel<<<sblocks, 256, 0, stream>>>(input_idx, ghist, E, bshift);
        scan_kernel<<<1, NB, 0, stream>>>(ghist, bbase, cursor);
        scatter_kernel<<<sblocks, 1024, 0, stream>>>(
            input_idx, weight_idx, cursor, sorted, E, bshift);

        edge_linear_sorted_kernel<<<NB * 2, 256, 0, stream>>>(
            values, (const uint32_t*)wbf, sorted, bbase, out, rows, bshift);
    } else if (ws_size >= need_wv) {
        uint16_t* wbf = (uint16_t*)d_ws;
        uint16_t* vbf = (uint16_t*)((char*)d_ws + v_off);
        int wn4 = NW / 4, vn4 = NV / 4;
        convert_w_kernel<<<(wn4 + 255) / 256, 256, 0, stream>>>(
            (const f32x4*)weights, (u16x4*)wbf, wn4);
        convert_v_kernel<<<(vn4 + 255) / 256, 256, 0, stream>>>(
            (const f32x4*)values, (u16x4*)vbf, vn4);
        edge_linear_bf16wv_kernel<<<grid, block, 0, stream>>>(
            (const uint32_t*)vbf, (const uint32_t*)wbf,
            input_idx, weight_idx, out, E);
    } else {
        edge_linear_f32_kernel<<<grid, block, 0, stream>>>(
            values, weights, input_idx, weight_idx, out, E);
    }
}

// Round 5
// 325.209 us; speedup vs baseline: 1.3365x; 1.3365x over previous
//
#include <hip/hip_runtime.h>
#include <hip/hip_bf16.h>
#include <stdint.h>

// Round-8: revert sort (r4: fetch dropped as designed but scattered-nt stores
// re-added the touch; sort passes cost 80us). Model locked over 5 rounds:
// time = (random line-touches/edge ~2.31) x (latency/outstanding ~10cy) per CU.
// Bytes, VALU, bank conflicts all irrelevant. This round raises the service
// rate: persistent grid-stride main (2048 blocks = 8/CU, all 32 waves/CU
// resident entire kernel; no 131K-block launch/drain boundaries -> sustained
// outstanding misses up ~10-18%). Converts fused to ONE grid-stride launch.
// nt is 3-for-3 harmful (r1 loads, r3 coalesced stores, r4 scattered stores):
// plain cached accesses everywhere.

typedef float          f32x4 __attribute__((ext_vector_type(4)));
typedef unsigned int   u32x4 __attribute__((ext_vector_type(4)));
typedef unsigned short u16x4 __attribute__((ext_vector_type(4)));

static __device__ __forceinline__ float bflo(uint32_t u) {
    union { uint32_t u; float f; } c; c.u = u << 16; return c.f;
}
static __device__ __forceinline__ float bfhi(uint32_t u) {
    union { uint32_t u; float f; } c; c.u = u & 0xffff0000u; return c.f;
}

// ---- fused fp32 -> bf16 convert of BOTH tables, one grid-stride launch ----
__global__ __launch_bounds__(256) void convert_tables_gs_kernel(
    const f32x4* __restrict__ wsrc, u16x4* __restrict__ wdst, int wn4,
    const f32x4* __restrict__ vsrc, u16x4* __restrict__ vdst, int vn4)
{
    int total  = wn4 + vn4;
    int stride = gridDim.x * 256;
    for (int i = blockIdx.x * 256 + threadIdx.x; i < total; i += stride) {
        const f32x4* src; u16x4* dst; int j;
        if (i < wn4) { src = wsrc; dst = wdst; j = i; }
        else         { src = vsrc; dst = vdst; j = i - wn4; }
        f32x4 v = src[j];
        u16x4 r;
        r.x = __bfloat16_as_ushort(__float2bfloat16(v.x));
        r.y = __bfloat16_as_ushort(__float2bfloat16(v.y));
        r.z = __bfloat16_as_ushort(__float2bfloat16(v.z));
        r.w = __bfloat16_as_ushort(__float2bfloat16(v.w));
        dst[j] = r;
    }
}

// ---- main: persistent grid-stride, thread-per-output, bf16 W and V ----
__global__ __launch_bounds__(256) void edge_linear_bf16wv_gs_kernel(
    const uint32_t* __restrict__ vbf,        // bf16[NUM_VALUES][8] as u32[.][4]
    const uint32_t* __restrict__ wbf,        // bf16[NUM_W][8][8]  as u32[.][32]
    const int*      __restrict__ input_idx,  // [E]
    const int*      __restrict__ weight_idx, // [E]
    float*          __restrict__ out,        // fp32[E][8]
    long long total)                         // E*8
{
    long long stride = (long long)gridDim.x * 256LL;
    for (long long gid = (long long)blockIdx.x * 256LL + threadIdx.x;
         gid < total; gid += stride) {
        int e = (int)(gid >> 3);
        int o = (int)(gid & 7);

        int iidx = input_idx[e];
        int widx = weight_idx[e];

        const u32x4* xp = (const u32x4*)(vbf + (size_t)(uint32_t)iidx * 4u);
        const u32x4* wp = (const u32x4*)(wbf + (size_t)(uint32_t)widx * 32u
                                             + (uint32_t)o * 4u);

        u32x4 wv = *wp;        // 1 random line-touch (W row, 16 B of its line)
        u32x4 xv = *xp;        // 1 random line-touch (x, 16 B broadcast/8 lanes)

        float acc = 0.0f;
        acc = fmaf(bflo(wv.x), bflo(xv.x), acc);
        acc = fmaf(bfhi(wv.x), bfhi(xv.x), acc);
        acc = fmaf(bflo(wv.y), bflo(xv.y), acc);
        acc = fmaf(bfhi(wv.y), bfhi(xv.y), acc);
        acc = fmaf(bflo(wv.z), bflo(xv.z), acc);
        acc = fmaf(bfhi(wv.z), bfhi(xv.z), acc);
        acc = fmaf(bflo(wv.w), bflo(xv.w), acc);
        acc = fmaf(bfhi(wv.w), bfhi(xv.w), acc);

        out[gid] = acc;        // coalesced: 0.25 line-touches/edge amortized
    }
}

// ---- f32 fallback (ws too small) ----
__global__ __launch_bounds__(256) void edge_linear_f32_kernel(
    const float* __restrict__ values,
    const float* __restrict__ weights,
    const int*   __restrict__ input_idx,
    const int*   __restrict__ weight_idx,
    float*       __restrict__ out,
    int E)
{
    int gid = blockIdx.x * blockDim.x + threadIdx.x;
    int e = gid >> 3;
    if (e >= E) return;
    int o = gid & 7;
    int iidx = input_idx[e];
    int widx = weight_idx[e];
    const float4* xp = (const float4*)(values  + (size_t)iidx * 8u);
    const float4* wp = (const float4*)(weights + (size_t)widx * 64u + (uint32_t)o * 8u);
    float4 x0 = xp[0], x1 = xp[1], w0 = wp[0], w1 = wp[1];
    float acc = 0.0f;
    acc = fmaf(w0.x, x0.x, acc); acc = fmaf(w0.y, x0.y, acc);
    acc = fmaf(w0.z, x0.z, acc); acc = fmaf(w0.w, x0.w, acc);
    acc = fmaf(w1.x, x1.x, acc); acc = fmaf(w1.y, x1.y, acc);
    acc = fmaf(w1.z, x1.z, acc); acc = fmaf(w1.w, x1.w, acc);
    out[gid] = acc;
}

extern "C" void kernel_launch(void* const* d_in, const int* in_sizes, int n_in,
                              void* d_out, int out_size, void* d_ws, size_t ws_size,
                              hipStream_t stream) {
    const float* values     = (const float*)d_in[0];
    const float* weights    = (const float*)d_in[1];
    const int*   input_idx  = (const int*)d_in[2];
    const int*   weight_idx = (const int*)d_in[3];
    float*       out        = (float*)d_out;

    int NV = in_sizes[0];               // floats in value table
    int NW = in_sizes[1];               // floats in weight table
    int E  = in_sizes[2];               // edges

    size_t need_w  = (size_t)NW * sizeof(uint16_t);
    size_t v_off   = (need_w + 255u) & ~(size_t)255u;
    size_t need_wv = v_off + (size_t)NV * sizeof(uint16_t);

    long long total = (long long)E * 8;

    if (ws_size >= need_wv) {
        uint16_t* wbf = (uint16_t*)d_ws;
        uint16_t* vbf = (uint16_t*)((char*)d_ws + v_off);
        int wn4 = NW / 4, vn4 = NV / 4;
        // persistent-style convert: 2048 blocks, pure streaming
        convert_tables_gs_kernel<<<2048, 256, 0, stream>>>(
            (const f32x4*)weights, (u16x4*)wbf, wn4,
            (const f32x4*)values,  (u16x4*)vbf, vn4);
        // persistent main: 8 blocks/CU x 256 CUs; each thread loops ~total/524288
        edge_linear_bf16wv_gs_kernel<<<2048, 256, 0, stream>>>(
            (const uint32_t*)vbf, (const uint32_t*)wbf,
            input_idx, weight_idx, out, total);
    } else {
        int grid = (int)((total + 255) / 256);
        edge_linear_f32_kernel<<<grid, 256, 0, stream>>>(
            values, weights, input_idx, weight_idx, out, E);
    }
}

// Round 7
// 319.563 us; speedup vs baseline: 1.3601x; 1.0177x over previous
//
#include <hip/hip_runtime.h>
#include <hip/hip_bf16.h>
#include <stdint.h>

// Round-9 (final polish, resubmit after infra failure): best-of-all-rounds.
//   main  = round-2 kernel exactly (bf16 W + bf16 V tables, plain cached
//           loads AND stores, exact-sized grid) -- best measured main 150.9us.
//   setup = round-3's single fused convert launch (both tables, one kernel).
// Locked model (6 experiments): time = 2 compulsory random line-touches/edge
// (W line + x line) x ~340cy capacity-bound avg latency / ~30 outstanding
// per-CU (HW MSHR cap). Bytes (r1/r4), nt steering (r1/r3/r4: 3-for-3
// negative), sort locality (r4: sort cost > gain), occupancy/persistence
// (r5: neutral), MLP (prior session: neutral) are all measured dead ends.
// This is the structural floor for the gather algorithm at this size.

typedef float          f32x4 __attribute__((ext_vector_type(4)));
typedef unsigned int   u32x4 __attribute__((ext_vector_type(4)));
typedef unsigned short u16x4 __attribute__((ext_vector_type(4)));

static __device__ __forceinline__ float bflo(uint32_t u) {
    union { uint32_t u; float f; } c; c.u = u << 16; return c.f;
}
static __device__ __forceinline__ float bfhi(uint32_t u) {
    union { uint32_t u; float f; } c; c.u = u & 0xffff0000u; return c.f;
}

// ---- fused fp32 -> bf16 convert of BOTH tables in one launch (RNE) ----
__global__ __launch_bounds__(256) void convert_tables_kernel(
    const f32x4* __restrict__ wsrc, u16x4* __restrict__ wdst, int wn4,
    const f32x4* __restrict__ vsrc, u16x4* __restrict__ vdst, int vn4)
{
    int i = blockIdx.x * blockDim.x + threadIdx.x;
    const f32x4* src; u16x4* dst; int j;
    if (i < wn4) { src = wsrc; dst = wdst; j = i; }
    else         { src = vsrc; dst = vdst; j = i - wn4; if (j >= vn4) return; }
    f32x4 v = src[j];
    u16x4 r;
    r.x = __bfloat16_as_ushort(__float2bfloat16(v.x));
    r.y = __bfloat16_as_ushort(__float2bfloat16(v.y));
    r.z = __bfloat16_as_ushort(__float2bfloat16(v.z));
    r.w = __bfloat16_as_ushort(__float2bfloat16(v.w));
    dst[j] = r;
}

// ---- main: thread-per-output, bf16 W and V, plain cached load/store ----
__global__ __launch_bounds__(256) void edge_linear_bf16wv_kernel(
    const uint32_t* __restrict__ vbf,        // bf16[NUM_VALUES][8] as u32[.][4]
    const uint32_t* __restrict__ wbf,        // bf16[NUM_W][8][8]  as u32[.][32]
    const int*      __restrict__ input_idx,  // [E]
    const int*      __restrict__ weight_idx, // [E]
    float*          __restrict__ out,        // fp32[E][8]
    int E)
{
    int gid = blockIdx.x * blockDim.x + threadIdx.x;
    int e = gid >> 3;
    if (e >= E) return;
    int o = gid & 7;

    int iidx = input_idx[e];
    int widx = weight_idx[e];

    const u32x4* xp = (const u32x4*)(vbf + (size_t)(uint32_t)iidx * 4u);
    const u32x4* wp = (const u32x4*)(wbf + (size_t)(uint32_t)widx * 32u
                                         + (uint32_t)o * 4u);

    u32x4 wv = *wp;        // random line-touch 1 (W row o: 16 B of its line)
    u32x4 xv = *xp;        // random line-touch 2 (x: 16 B, broadcast to 8 lanes)

    float acc = 0.0f;
    acc = fmaf(bflo(wv.x), bflo(xv.x), acc);
    acc = fmaf(bfhi(wv.x), bfhi(xv.x), acc);
    acc = fmaf(bflo(wv.y), bflo(xv.y), acc);
    acc = fmaf(bfhi(wv.y), bfhi(xv.y), acc);
    acc = fmaf(bflo(wv.z), bflo(xv.z), acc);
    acc = fmaf(bfhi(wv.z), bfhi(xv.z), acc);
    acc = fmaf(bflo(wv.w), bflo(xv.w), acc);
    acc = fmaf(bfhi(wv.w), bfhi(xv.w), acc);

    out[gid] = acc;        // coalesced, cached (nt measured harmful)
}

// ---- f32 fallback (ws too small) ----
__global__ __launch_bounds__(256) void edge_linear_f32_kernel(
    const float* __restrict__ values,
    const float* __restrict__ weights,
    const int*   __restrict__ input_idx,
    const int*   __restrict__ weight_idx,
    float*       __restrict__ out,
    int E)
{
    int gid = blockIdx.x * blockDim.x + threadIdx.x;
    int e = gid >> 3;
    if (e >= E) return;
    int o = gid & 7;
    int iidx = input_idx[e];
    int widx = weight_idx[e];
    const float4* xp = (const float4*)(values  + (size_t)iidx * 8u);
    const float4* wp = (const float4*)(weights + (size_t)widx * 64u + (uint32_t)o * 8u);
    float4 x0 = xp[0], x1 = xp[1], w0 = wp[0], w1 = wp[1];
    float acc = 0.0f;
    acc = fmaf(w0.x, x0.x, acc); acc = fmaf(w0.y, x0.y, acc);
    acc = fmaf(w0.z, x0.z, acc); acc = fmaf(w0.w, x0.w, acc);
    acc = fmaf(w1.x, x1.x, acc); acc = fmaf(w1.y, x1.y, acc);
    acc = fmaf(w1.z, x1.z, acc); acc = fmaf(w1.w, x1.w, acc);
    out[gid] = acc;
}

extern "C" void kernel_launch(void* const* d_in, const int* in_sizes, int n_in,
                              void* d_out, int out_size, void* d_ws, size_t ws_size,
                              hipStream_t stream) {
    const float* values     = (const float*)d_in[0];
    const float* weights    = (const float*)d_in[1];
    const int*   input_idx  = (const int*)d_in[2];
    const int*   weight_idx = (const int*)d_in[3];
    float*       out        = (float*)d_out;

    int NV = in_sizes[0];               // floats in value table
    int NW = in_sizes[1];               // floats in weight table
    int E  = in_sizes[2];               // edges

    size_t need_w  = (size_t)NW * sizeof(uint16_t);          // 8.4 MB
    size_t v_off   = (need_w + 255u) & ~(size_t)255u;
    size_t need_wv = v_off + (size_t)NV * sizeof(uint16_t);  // + 16.8 MB

    long long threads = (long long)E * 8;
    int block = 256;
    int grid = (int)((threads + block - 1) / block);

    if (ws_size >= need_wv) {
        uint16_t* wbf = (uint16_t*)d_ws;
        uint16_t* vbf = (uint16_t*)((char*)d_ws + v_off);
        int wn4 = NW / 4, vn4 = NV / 4;
        int tn4 = wn4 + vn4;
        convert_tables_kernel<<<(tn4 + 255) / 256, 256, 0, stream>>>(
            (const f32x4*)weights, (u16x4*)wbf, wn4,
            (const f32x4*)values,  (u16x4*)vbf, vn4);
        edge_linear_bf16wv_kernel<<<grid, block, 0, stream>>>(
            (const uint32_t*)vbf, (const uint32_t*)wbf,
            input_idx, weight_idx, out, E);
    } else {
        edge_linear_f32_kernel<<<grid, block, 0, stream>>>(
            values, weights, input_idx, weight_idx, out, E);
    }
}